// Round 5
// baseline (171.156 us; speedup 1.0000x reference)
//
#include <hip/hip_runtime.h>
#include <hip/hip_bf16.h>

// FlippedQuanv3x3 == 3x3 conv (C=16 -> O=64, pad=1) with transformed weight
// Weff[o,c,k9] = 0.25*(sum_i w[o,c,i]*A[i,k9] + t0[k9]).
// Implicit GEMM, bf16 MFMA 16x16x32. K order = tap-major: k = tap*16 + c.
// K = 144 padded to 160 = 5 chunks. A = im2col(x) (M = pixels), B = Weff (N = o).
//
// R8 (read-path fix; single variable vs R7): staging reads were 8 scalar 4-B
// loads/thread plane-hopping @64-KiB stride -> 256-B DRAM runs, ~32K
// concurrent streams chipwide -> page thrash + bus turnarounds degrade ALL
// traffic (explains R5/R6/R7 neutrality: they never touched reads).
// Now: thread <- (row, chalf, w-quad); 8 x global_load_dwordx4 (16 B/lane,
// ~544-B contiguous runs/instr, 4x fewer read instrs, 4x bytes in flight) +
// 4 x ds_write_b128 into the SAME el() LDS layout (hot loop untouched).
// Halo quads (wq=0,33) and OOB rows are all-zero -> no straddle, aligned.
// Known cost: b128 LDS writes bank-collapse (~+600 cyc/block, LDS pipe has
// 3x headroom). Numerics bit-identical (same pk_bf16, same MFMA chain).

typedef short bf16x8 __attribute__((ext_vector_type(8)));   // 8 bf16 = 4 VGPR
typedef float f32x4 __attribute__((ext_vector_type(4)));
typedef unsigned u32x4 __attribute__((ext_vector_type(4)));

// ---- Pauli feature constants (verified R1-R3) ----
__device__ __forceinline__ void pauli_entry(int s, int r, int c, float& re, float& im) {
    re = 0.f; im = 0.f;
    if (s == 0)      { if (r == c) re = 1.f; }
    else if (s == 1) { if (r != c) re = 1.f; }
    else if (s == 2) { if (r == 0 && c == 1) im = -1.f; else if (r == 1 && c == 0) im = 1.f; }
    else             { if (r == c) re = (r == 0) ? 1.f : -1.f; }
}

__device__ __forceinline__ float A_entry(int i, int k) {
    int j = i + 1, sa = j >> 2, sb = j & 3;
    int r = k >> 2, c = k & 3;        // 4x4 flat embedding (M.flat[k]) — verified R1
    float ar, ai, br, bi;
    pauli_entry(sa, r >> 1, c >> 1, ar, ai);
    pauli_entry(sb, r & 1, c & 1, br, bi);
    float re1 = ar * br - ai * bi;
    pauli_entry(sa, c >> 1, r >> 1, ar, ai);
    pauli_entry(sb, c & 1, r & 1, br, bi);
    float re2 = ar * br - ai * bi;
    return 0.5f * (re1 + re2);
}

__device__ __forceinline__ short f2bf(float f) {   // RNE float->bf16 bits
    union { float f; unsigned int u; } a; a.f = f;
    unsigned int r = a.u + 0x7fffu + ((a.u >> 16) & 1u);
    return (short)(r >> 16);
}

// pack two floats -> two bf16 (RNE) in one u32 (lo = a, hi = b)
__device__ __forceinline__ unsigned pk_bf16(float a, float b) {
#if __has_builtin(__builtin_amdgcn_cvt_pk_bf16_f32)
    typedef __bf16 bf2 __attribute__((ext_vector_type(2)));
    bf2 r = __builtin_amdgcn_cvt_pk_bf16_f32(a, b);
    union { bf2 v; unsigned u; } cv; cv.v = r;
    return cv.u;
#else
    union { float f; unsigned u; } x, y; x.f = a; y.f = b;
    unsigned ra = x.u + 0x7fffu + ((x.u >> 16) & 1u);
    unsigned rb = y.u + 0x7fffu + ((y.u >> 16) & 1u);
    return (ra >> 16) | (rb & 0xffff0000u);
#endif
}

// ---- prep: Weff as MFMA B-fragments, k tap-major.
// bfrag[(chunk*4 + ot)*64 + lane][j] = Weff[o = ot*16 + (lane&15)]
//   [gk = chunk*32 + (lane>>4)*8 + j], gk -> (tap = gk>>4, c = gk&15); 0 if gk>=144.
__global__ __launch_bounds__(256) void prep_kernel(const float* __restrict__ weight,
                                                   short* __restrict__ bfrag) {
    __shared__ float Ash[135];       // Ash[i*9 + tap] = A[i, tap]
    int tid = threadIdx.x;
    if (tid < 135) Ash[tid] = A_entry(tid / 9, tid % 9);
    __syncthreads();

    int t = blockIdx.x * 256 + tid;
    if (t >= 1280) return;
    int lane  = t & 63;
    int ot    = (t >> 6) & 3;
    int chunk = t >> 8;
    int q     = lane >> 4;
    int o     = ot * 16 + (lane & 15);
    short vals[8];
    #pragma unroll
    for (int j = 0; j < 8; ++j) {
        int gk = chunk * 32 + q * 8 + j;
        float v = 0.f;
        if (gk < 144) {
            int tap = gk >> 4;         // patch index 0..8
            int c   = gk & 15;         // channel
            float acc = (tap == 0 || tap == 5) ? 1.f : 0.f;   // t0
            const float* w = weight + (o * 16 + c) * 15;
            #pragma unroll
            for (int i = 0; i < 15; ++i) acc += w[i] * Ash[i * 9 + tap];
            v = 0.25f * acc;
        }
        vals[j] = f2bf(v);
    }
    *(bf16x8*)(bfrag + t * 8) = *(bf16x8*)vals;
}

// LDS x-tile: el(row, w, c) = (row*136 + w)*16 + slot*8 + (c&7),
// slot = (c>>3) ^ ((w>>2)&1). row in [0,6) = x rows h0-1..h0+4; w in [0,136)
// = x w -4..131. Row stride 4352 B == 0 mod 32 banks; hot-loop b128 reads
// <=2-way conflicted (free, m136).
__global__ __launch_bounds__(256, 4) void conv_mfma(const float* __restrict__ x,
                                                    const short* __restrict__ bfrag,
                                                    const float* __restrict__ bias,
                                                    float* __restrict__ out) {
    __shared__ short sx[6 * 136 * 16];   // 26112 B -> 4 blocks/CU

    const int tid  = threadIdx.x;
    const int h0   = blockIdx.x * 4;
    const int b    = blockIdx.y;
    const int lane = tid & 63;
    const int wave = tid >> 6;
    const int q    = lane >> 4;
    const int nlo  = lane & 15;
    const int otp  = wave >> 1;       // ot-pair: owns o-groups {otp*2, otp*2+1}
    const int rh   = wave & 1;        // row-half: owns output rows rh*2, rh*2+1

    // ---- stage x -> bf16 c-fastest LDS tile (R8 vectorized read path).
    // 408 tasks = 6 rows x 2 chalf x 34 w-quads; task = 8 x dwordx4 (one per
    // c-plane) + 4 x ds_write_b128. Interior quads (1..32) are aligned,
    // fully in-bounds; wq 0/33 and OOB rows write zeros (halo).
    const float* xb = x + (size_t)b * 16 * 128 * 128;
    #pragma unroll
    for (int it = 0; it < 2; ++it) {
        int pos = tid + it * 256;
        if (pos < 408) {
            int seg = pos / 34;            // row*2 + chalf
            int wq  = pos - seg * 34;      // w-quad 0..33
            int row = seg >> 1, chalf = seg & 1;
            int hp  = h0 - 1 + row;
            int w   = wq * 4;              // LDS w base (w..w+3)
            int xw  = w - 4;               // x w base
            bool ok = ((unsigned)hp < 128u) && (wq >= 1) && (wq <= 32);
            const float* src = xb + (size_t)(chalf * 8) * 16384 + hp * 128 + xw;
            f32x4 v[8];
            f32x4 z = { 0.f, 0.f, 0.f, 0.f };
            #pragma unroll
            for (int j = 0; j < 8; ++j)
                v[j] = ok ? *(const f32x4*)(src + (size_t)j * 16384) : z;
            int slot = (chalf ^ wq) & 1;   // (w+wi)>>2 == wq for wi 0..3
            #pragma unroll
            for (int wi = 0; wi < 4; ++wi) {
                u32x4 d;
                #pragma unroll
                for (int p = 0; p < 4; ++p)
                    d[p] = pk_bf16(v[2 * p][wi], v[2 * p + 1][wi]);
                *(u32x4*)((unsigned*)sx + (row * 136 + w + wi) * 8 + slot * 4) = d;
            }
        }
    }

    // ---- weights for this wave's 2 o-groups (40 VGPR), bias per lane
    bf16x8 Breg[10];
    #pragma unroll
    for (int ch = 0; ch < 5; ++ch)
        #pragma unroll
        for (int j = 0; j < 2; ++j)
            Breg[ch * 2 + j] = *(const bf16x8*)(bfrag + ((ch * 4 + otp * 2 + j) * 64 + lane) * 8);
    float bv[2];
    #pragma unroll
    for (int j = 0; j < 2; ++j) bv[j] = bias[(otp * 2 + j) * 16 + nlo];

    // ---- per-chunk A-read base; r (row 0..1) and np are imm offsets
    int baseA[5];
    #pragma unroll
    for (int ch = 0; ch < 5; ++ch) {
        int tap = ch * 2 + (q >> 1);
        if (tap > 8) tap = 8;             // chunk 4 upper half: pad, B=0
        int kh = tap / 3, kw = tap - 3 * kh;
        int chalf = q & 1;
        int row0  = rh * 2 + kh;
        int w0    = nlo + kw + 3;         // LDS w-index for pixel nlo
        int slot  = (chalf ^ (w0 >> 2)) & 1;
        baseA[ch] = (row0 * 136 + w0) * 16 + slot * 8;
    }
    __syncthreads();

    // ---- hot loop: 2 rows x 4 pixel-groups; per np: 5 chunks x (2 rd + 4 mfma),
    // then direct dwordx4 stores (R0-proven epilogue).
    #pragma unroll
    for (int r = 0; r < 2; ++r) {
        const int h = h0 + rh * 2 + r;
        #pragma unroll
        for (int np = 0; np < 4; ++np) {
            f32x4 acc[2][2];              // [ot-in-pair][mt] = 16 VGPR
            #pragma unroll
            for (int j = 0; j < 2; ++j) {
                f32x4 ini = { bv[j], bv[j], bv[j], bv[j] };
                acc[j][0] = ini;
                acc[j][1] = ini;
            }
            #pragma unroll
            for (int ch = 0; ch < 5; ++ch) {
                const short* pA = sx + baseA[ch] + r * 2176 + np * 512;
                bf16x8 A0 = *(const bf16x8*)(pA);        // pixels np*32+0..15
                bf16x8 A1 = *(const bf16x8*)(pA + 256);  // pixels np*32+16..31
                #pragma unroll
                for (int j = 0; j < 2; ++j) {
                    acc[j][0] = __builtin_amdgcn_mfma_f32_16x16x32_bf16(A0, Breg[ch * 2 + j], acc[j][0], 0, 0, 0);
                    acc[j][1] = __builtin_amdgcn_mfma_f32_16x16x32_bf16(A1, Breg[ch * 2 + j], acc[j][1], 0, 0, 0);
                }
            }
            // D[m = q*4+reg (pixel), n = nlo (o)] -> dwordx4 per (mt, j)
            #pragma unroll
            for (int j = 0; j < 2; ++j) {
                float* dst = out + (((size_t)b * 64 + (otp * 2 + j) * 16 + nlo) * 128 + h) * 128
                           + np * 32 + q * 4;
                *(f32x4*)dst        = acc[j][0];
                *(f32x4*)(dst + 16) = acc[j][1];
            }
        }
    }
}

extern "C" void kernel_launch(void* const* d_in, const int* in_sizes, int n_in,
                              void* d_out, int out_size, void* d_ws, size_t ws_size,
                              hipStream_t stream) {
    const float* x      = (const float*)d_in[0];   // [32,16,128,128]
    const float* weight = (const float*)d_in[1];   // [64,16,15]
    const float* bias   = (const float*)d_in[2];   // [64,1]
    float* out   = (float*)d_out;                  // [32,64,128,128]
    short* bfrag = (short*)d_ws;                   // 1280*8 bf16 = 20 KB

    prep_kernel<<<5, 256, 0, stream>>>(weight, bfrag);
    dim3 grid(32, 32);                             // (h-tiles of 4 rows, b) = 4 blocks/CU
    conv_mfma<<<grid, 256, 0, stream>>>(x, bfrag, bias, out);
}

// Round 6
// 168.990 us; speedup vs baseline: 1.0128x; 1.0128x over previous
//
#include <hip/hip_runtime.h>
#include <hip/hip_bf16.h>

// FlippedQuanv3x3 == 3x3 conv (C=16 -> O=64, pad=1) with transformed weight
// Weff[o,c,k9] = 0.25*(sum_i w[o,c,i]*A[i,k9] + t0[k9]).
// Implicit GEMM, bf16 MFMA 16x16x32. K order = tap-major: k = tap*16 + c.
// K = 144 padded to 160 = 5 chunks. A = im2col(x) (M = pixels), B = Weff (N = o).
//
// R9 = R7 (best, 166.9us) + XCD-aware block swizzle (T1), single variable.
// Ledger: nt stores +21, store-run-length 0, occupancy x2 -2.5, read-vec +4.
// All source-side patterns null -> memory-system-bound at ~2.7 TB/s while
// harness fill hits 6.9 on the same buffers. Last untouched locality lever:
// default dispatch round-robins adjacent h-tiles (halo-sharing, write-adjacent)
// across all 8 XCDs. Swizzle nl=(hw%8)*128+hw/8 (bijective, 1024%8==0):
// XCD x owns b in {4x..4x+3}, h-tiles in order -> halo rows fetched once per
// XCD-L2 (reads 50->~37 MB HBM-side) and per-XCD dirty set confined to a
// contiguous ~17-MB slab instead of the full 137 MB.
// Numerics bit-identical to R7 (same staging, same MFMA chain, same stores).

typedef short bf16x8 __attribute__((ext_vector_type(8)));   // 8 bf16 = 4 VGPR
typedef float f32x4 __attribute__((ext_vector_type(4)));

// ---- Pauli feature constants (verified R1-R3) ----
__device__ __forceinline__ void pauli_entry(int s, int r, int c, float& re, float& im) {
    re = 0.f; im = 0.f;
    if (s == 0)      { if (r == c) re = 1.f; }
    else if (s == 1) { if (r != c) re = 1.f; }
    else if (s == 2) { if (r == 0 && c == 1) im = -1.f; else if (r == 1 && c == 0) im = 1.f; }
    else             { if (r == c) re = (r == 0) ? 1.f : -1.f; }
}

__device__ __forceinline__ float A_entry(int i, int k) {
    int j = i + 1, sa = j >> 2, sb = j & 3;
    int r = k >> 2, c = k & 3;        // 4x4 flat embedding (M.flat[k]) — verified R1
    float ar, ai, br, bi;
    pauli_entry(sa, r >> 1, c >> 1, ar, ai);
    pauli_entry(sb, r & 1, c & 1, br, bi);
    float re1 = ar * br - ai * bi;
    pauli_entry(sa, c >> 1, r >> 1, ar, ai);
    pauli_entry(sb, c & 1, r & 1, br, bi);
    float re2 = ar * br - ai * bi;
    return 0.5f * (re1 + re2);
}

__device__ __forceinline__ short f2bf(float f) {   // RNE float->bf16 bits
    union { float f; unsigned int u; } a; a.f = f;
    unsigned int r = a.u + 0x7fffu + ((a.u >> 16) & 1u);
    return (short)(r >> 16);
}

// pack two floats -> two bf16 (RNE) in one u32 (lo = a, hi = b)
__device__ __forceinline__ unsigned pk_bf16(float a, float b) {
#if __has_builtin(__builtin_amdgcn_cvt_pk_bf16_f32)
    typedef __bf16 bf2 __attribute__((ext_vector_type(2)));
    bf2 r = __builtin_amdgcn_cvt_pk_bf16_f32(a, b);
    union { bf2 v; unsigned u; } cv; cv.v = r;
    return cv.u;
#else
    union { float f; unsigned u; } x, y; x.f = a; y.f = b;
    unsigned ra = x.u + 0x7fffu + ((x.u >> 16) & 1u);
    unsigned rb = y.u + 0x7fffu + ((y.u >> 16) & 1u);
    return (ra >> 16) | (rb & 0xffff0000u);
#endif
}

// ---- prep: Weff as MFMA B-fragments, k tap-major.
// bfrag[(chunk*4 + ot)*64 + lane][j] = Weff[o = ot*16 + (lane&15)]
//   [gk = chunk*32 + (lane>>4)*8 + j], gk -> (tap = gk>>4, c = gk&15); 0 if gk>=144.
__global__ __launch_bounds__(256) void prep_kernel(const float* __restrict__ weight,
                                                   short* __restrict__ bfrag) {
    __shared__ float Ash[135];       // Ash[i*9 + tap] = A[i, tap]
    int tid = threadIdx.x;
    if (tid < 135) Ash[tid] = A_entry(tid / 9, tid % 9);
    __syncthreads();

    int t = blockIdx.x * 256 + tid;
    if (t >= 1280) return;
    int lane  = t & 63;
    int ot    = (t >> 6) & 3;
    int chunk = t >> 8;
    int q     = lane >> 4;
    int o     = ot * 16 + (lane & 15);
    short vals[8];
    #pragma unroll
    for (int j = 0; j < 8; ++j) {
        int gk = chunk * 32 + q * 8 + j;
        float v = 0.f;
        if (gk < 144) {
            int tap = gk >> 4;         // patch index 0..8
            int c   = gk & 15;         // channel
            float acc = (tap == 0 || tap == 5) ? 1.f : 0.f;   // t0
            const float* w = weight + (o * 16 + c) * 15;
            #pragma unroll
            for (int i = 0; i < 15; ++i) acc += w[i] * Ash[i * 9 + tap];
            v = 0.25f * acc;
        }
        vals[j] = f2bf(v);
    }
    *(bf16x8*)(bfrag + t * 8) = *(bf16x8*)vals;
}

// LDS x-tile: el(row, w, c) = (row*136 + w)*16 + slot*8 + (c&7),
// slot = (c>>3) ^ ((w>>2)&1). row in [0,6) = x rows h0-1..h0+4; w in [0,136)
// = x w -4..131. Row stride 4352 B == 0 mod 32 banks; hot-loop b128 reads
// <=2-way conflicted (free, m136).
__global__ __launch_bounds__(256, 4) void conv_mfma(const float* __restrict__ x,
                                                    const short* __restrict__ bfrag,
                                                    const float* __restrict__ bias,
                                                    float* __restrict__ out) {
    __shared__ short sx[6 * 136 * 16];   // 26112 B -> 4 blocks/CU

    const int tid  = threadIdx.x;

    // ---- XCD-aware swizzle (T1). HW linear id hw = ht + 32*b dispatches
    // round-robin hw%8 -> XCD. Remap so XCD x gets nl in [x*128,(x+1)*128):
    // b = nl>>5 in {4x..4x+3}, h-tiles in order. Bijective (1024 % 8 == 0).
    const int hw  = blockIdx.x + (int)gridDim.x * blockIdx.y;
    const int nl  = (hw & 7) * 128 + (hw >> 3);
    const int b   = nl >> 5;
    const int h0  = (nl & 31) * 4;

    const int lane = tid & 63;
    const int wave = tid >> 6;
    const int q    = lane >> 4;
    const int nlo  = lane & 15;
    const int otp  = wave >> 1;       // ot-pair: owns o-groups {otp*2, otp*2+1}
    const int rh   = wave & 1;        // row-half: owns output rows rh*2, rh*2+1

    // ---- stage x -> bf16 c-fastest LDS tile. 1632 positions = (row,chalf,w).
    const float* xb = x + (size_t)b * 16 * 128 * 128;
    #pragma unroll
    for (int it = 0; it < 7; ++it) {
        int pos = tid + it * 256;
        if (pos < 1632) {
            int seg = pos / 136;           // row*2 + chalf
            int w   = pos - seg * 136;
            int row = seg >> 1, chalf = seg & 1;
            int hp  = h0 - 1 + row;
            int xw  = w - 4;
            bool ok = ((unsigned)hp < 128u) && ((unsigned)xw < 128u);
            const float* src = xb + (size_t)(chalf * 8) * 16384 + hp * 128 + xw;
            float v[8];
            #pragma unroll
            for (int j = 0; j < 8; ++j)
                v[j] = ok ? src[(size_t)j * 16384] : 0.f;
            int slot = (chalf ^ (w >> 2)) & 1;
            unsigned* dst = (unsigned*)sx + (row * 136 + w) * 8 + slot * 4;
            #pragma unroll
            for (int j2 = 0; j2 < 4; ++j2)
                dst[j2] = pk_bf16(v[2 * j2], v[2 * j2 + 1]);
        }
    }

    // ---- weights for this wave's 2 o-groups (40 VGPR), bias per lane
    bf16x8 Breg[10];
    #pragma unroll
    for (int ch = 0; ch < 5; ++ch)
        #pragma unroll
        for (int j = 0; j < 2; ++j)
            Breg[ch * 2 + j] = *(const bf16x8*)(bfrag + ((ch * 4 + otp * 2 + j) * 64 + lane) * 8);
    float bv[2];
    #pragma unroll
    for (int j = 0; j < 2; ++j) bv[j] = bias[(otp * 2 + j) * 16 + nlo];

    // ---- per-chunk A-read base; r (row 0..1) and np are imm offsets
    int baseA[5];
    #pragma unroll
    for (int ch = 0; ch < 5; ++ch) {
        int tap = ch * 2 + (q >> 1);
        if (tap > 8) tap = 8;             // chunk 4 upper half: pad, B=0
        int kh = tap / 3, kw = tap - 3 * kh;
        int chalf = q & 1;
        int row0  = rh * 2 + kh;
        int w0    = nlo + kw + 3;         // LDS w-index for pixel nlo
        int slot  = (chalf ^ (w0 >> 2)) & 1;
        baseA[ch] = (row0 * 136 + w0) * 16 + slot * 8;
    }
    __syncthreads();

    // ---- hot loop: 2 rows x 4 pixel-groups; per np: 5 chunks x (2 rd + 4 mfma),
    // then direct dwordx4 stores (R0-proven epilogue).
    #pragma unroll
    for (int r = 0; r < 2; ++r) {
        const int h = h0 + rh * 2 + r;
        #pragma unroll
        for (int np = 0; np < 4; ++np) {
            f32x4 acc[2][2];              // [ot-in-pair][mt] = 16 VGPR
            #pragma unroll
            for (int j = 0; j < 2; ++j) {
                f32x4 ini = { bv[j], bv[j], bv[j], bv[j] };
                acc[j][0] = ini;
                acc[j][1] = ini;
            }
            #pragma unroll
            for (int ch = 0; ch < 5; ++ch) {
                const short* pA = sx + baseA[ch] + r * 2176 + np * 512;
                bf16x8 A0 = *(const bf16x8*)(pA);        // pixels np*32+0..15
                bf16x8 A1 = *(const bf16x8*)(pA + 256);  // pixels np*32+16..31
                #pragma unroll
                for (int j = 0; j < 2; ++j) {
                    acc[j][0] = __builtin_amdgcn_mfma_f32_16x16x32_bf16(A0, Breg[ch * 2 + j], acc[j][0], 0, 0, 0);
                    acc[j][1] = __builtin_amdgcn_mfma_f32_16x16x32_bf16(A1, Breg[ch * 2 + j], acc[j][1], 0, 0, 0);
                }
            }
            // D[m = q*4+reg (pixel), n = nlo (o)] -> dwordx4 per (mt, j)
            #pragma unroll
            for (int j = 0; j < 2; ++j) {
                float* dst = out + (((size_t)b * 64 + (otp * 2 + j) * 16 + nlo) * 128 + h) * 128
                           + np * 32 + q * 4;
                *(f32x4*)dst        = acc[j][0];
                *(f32x4*)(dst + 16) = acc[j][1];
            }
        }
    }
}

extern "C" void kernel_launch(void* const* d_in, const int* in_sizes, int n_in,
                              void* d_out, int out_size, void* d_ws, size_t ws_size,
                              hipStream_t stream) {
    const float* x      = (const float*)d_in[0];   // [32,16,128,128]
    const float* weight = (const float*)d_in[1];   // [64,16,15]
    const float* bias   = (const float*)d_in[2];   // [64,1]
    float* out   = (float*)d_out;                  // [32,64,128,128]
    short* bfrag = (short*)d_ws;                   // 1280*8 bf16 = 20 KB

    prep_kernel<<<5, 256, 0, stream>>>(weight, bfrag);
    dim3 grid(32, 32);                             // (h-tiles of 4 rows, b) = 4 blocks/CU
    conv_mfma<<<grid, 256, 0, stream>>>(x, bfrag, bias, out);
}